// Round 1
// baseline (2662.423 us; speedup 1.0000x reference)
//
#include <hip/hip_runtime.h>
#include <math.h>

#define BB 64
#define TT 1024
#define II 256
#define HD 256

typedef unsigned short ushort_t;
typedef unsigned int uint_t;

// MFMA fragment types (guide-verified: short8 A/B frags, f32x4 acc)
typedef short sh8 __attribute__((ext_vector_type(8)));
typedef float fx4 __attribute__((ext_vector_type(4)));

// ---- bf16 helpers (manual, RNE) -------------------------------------------
__device__ __forceinline__ ushort_t f2bf(float f) {
    uint_t u = __float_as_uint(f);
    uint_t r = (u + 0x7fffu + ((u >> 16) & 1u)) >> 16;
    return (ushort_t)r;
}
__device__ __forceinline__ float bf2f(ushort_t v) {
    return __uint_as_float(((uint_t)v) << 16);
}

__device__ __forceinline__ float fast_rcp(float x) {
#if __has_builtin(__builtin_amdgcn_rcpf)
    return __builtin_amdgcn_rcpf(x);
#else
    return 1.f / x;
#endif
}
__device__ __forceinline__ float sigm(float x) {
    return fast_rcp(1.f + __expf(-x));
}
__device__ __forceinline__ float tanh_fast(float x) {
    return 1.f - 2.f * fast_rcp(1.f + __expf(2.f * x));
}

__device__ __forceinline__ fx4 mfma16(sh8 a, sh8 b, fx4 c) {
    return __builtin_amdgcn_mfma_f32_16x16x32_bf16(a, b, c, 0, 0, 0);
}

// async global->LDS, 16B per lane. Both pointers are PER-LANE (base + lane*16);
// HW takes readfirstlane(lds)=wave base and adds lane*16, matching exactly.
__device__ __forceinline__ void async_g2l(const ushort_t* g, ushort_t* l) {
#if __has_builtin(__builtin_amdgcn_global_load_lds)
    __builtin_amdgcn_global_load_lds(
        (const __attribute__((address_space(1))) unsigned int*)g,
        (__attribute__((address_space(3))) unsigned int*)l, 16, 0, 0);
#else
    *reinterpret_cast<uint4*>(l) = *reinterpret_cast<const uint4*>(g);
#endif
}

// raw barrier: drain LDS ops, do NOT drain vmcnt (avoids __syncthreads'
// per-step store/async-load drain; vmcnt is waited explicitly where needed)
#define BAR() asm volatile("s_waitcnt lgkmcnt(0)\n\ts_barrier" ::: "memory")

// ---------------------------------------------------------------------------
// Kernel 0: prepack recurrent weights fp32 W[k][j] -> bf16 W^T:  T[j*256+k]
// (B-fragment for mfma_16x16x32: lane l holds B[k=(l>>4)*8+i][n=l&15], i.e.
//  8 k-contiguous bf16 from row n of W^T -> one ds/global b128 per frag)
// ---------------------------------------------------------------------------
__global__ __launch_bounds__(256) void prepack_kernel(
    const float* __restrict__ Wz, const float* __restrict__ Wr,
    const float* __restrict__ Wh,
    ushort_t* __restrict__ Tz, ushort_t* __restrict__ Tr,
    ushort_t* __restrict__ Th)
{
    const int idx = blockIdx.x * 256 + threadIdx.x;  // 0..65535
    const int j = idx >> 8;
    const int k = idx & 255;
    const float* W = (blockIdx.y == 0) ? Wz : (blockIdx.y == 1) ? Wr : Wh;
    ushort_t* T = (blockIdx.y == 0) ? Tz : (blockIdx.y == 1) ? Tr : Th;
    T[idx] = f2bf(W[k * HD + j]);
}

// ---------------------------------------------------------------------------
// Kernel 1: input projection GEMM -> bf16 x5[t][bg][g][j][b16]
// Block = 16 batches (bg) x 4 timesteps x 64 cols of one gate g.
// Same fp32 GEMM core as before; only the M-row mapping and the epilogue
// change. Epilogue stages [ti][j][bi] in LDS then writes 2KB-contiguous
// uint4 runs (the [j][b16] packing is produced entirely by this block).
// ---------------------------------------------------------------------------
__global__ __launch_bounds__(256) void proj_kernel(
    const float* __restrict__ X,
    const float* __restrict__ Wz, const float* __restrict__ Wr,
    const float* __restrict__ Wh,
    const float* __restrict__ bz, const float* __restrict__ br,
    const float* __restrict__ bh,
    ushort_t* __restrict__ x5)
{
    __shared__ float As[64][36];
    __shared__ float Bs[32][64];
    __shared__ ushort_t ep[4 * 64 * 16];  // [ti][j(64)][bi(16)] = 8KB

    const int tid  = threadIdx.x;
    const int tx   = tid & 15;
    const int ty   = tid >> 4;
    const int bg   = blockIdx.x >> 8;          // batch group 0..3
    const int t0   = (blockIdx.x & 255) * 4;   // timestep base
    const int g    = blockIdx.y >> 2;
    const int col0 = (blockIdx.y & 3) * 64;

    const float* W    = (g == 0) ? Wz : (g == 1) ? Wr : Wh;
    const float* bias = (g == 0) ? bz : (g == 1) ? br : bh;

    float acc[4][4];
#pragma unroll
    for (int i = 0; i < 4; ++i)
#pragma unroll
        for (int j = 0; j < 4; ++j) acc[i][j] = 0.f;

    for (int k0 = 0; k0 < II; k0 += 32) {
        int fi = tid;
#pragma unroll
        for (int rp = 0; rp < 2; ++rp, fi += 256) {
            const int row = fi >> 3;       // 0..63: bi = row>>2, ti = row&3
            const int fc  = fi & 7;
            const size_t m = (size_t)(bg * 16 + (row >> 2)) * 1024 + t0 + (row & 3);
            const float4 v = *reinterpret_cast<const float4*>(
                X + m * II + k0 + fc * 4);
            *reinterpret_cast<float4*>(&As[row][fc * 4]) = v;
        }
        fi = tid;
#pragma unroll
        for (int rp = 0; rp < 2; ++rp, fi += 256) {
            const int row = fi >> 4;
            const int fc  = fi & 15;
            const float4 v = *reinterpret_cast<const float4*>(
                W + (size_t)(k0 + row) * HD + col0 + fc * 4);
            *reinterpret_cast<float4*>(&Bs[row][fc * 4]) = v;
        }
        __syncthreads();

#pragma unroll
        for (int kk = 0; kk < 32; ++kk) {
            const float a0 = As[ty * 4 + 0][kk];
            const float a1 = As[ty * 4 + 1][kk];
            const float a2 = As[ty * 4 + 2][kk];
            const float a3 = As[ty * 4 + 3][kk];
            const float4 bv = *reinterpret_cast<const float4*>(&Bs[kk][tx * 4]);
            acc[0][0] += a0 * bv.x; acc[0][1] += a0 * bv.y;
            acc[0][2] += a0 * bv.z; acc[0][3] += a0 * bv.w;
            acc[1][0] += a1 * bv.x; acc[1][1] += a1 * bv.y;
            acc[1][2] += a1 * bv.z; acc[1][3] += a1 * bv.w;
            acc[2][0] += a2 * bv.x; acc[2][1] += a2 * bv.y;
            acc[2][2] += a2 * bv.z; acc[2][3] += a2 * bv.w;
            acc[3][0] += a3 * bv.x; acc[3][1] += a3 * bv.y;
            acc[3][2] += a3 * bv.z; acc[3][3] += a3 * bv.w;
        }
        __syncthreads();
    }

    // thread (tx,ty) holds rows r=ty*4+i -> bi=ty, ti=i; cols col0+tx*4+jj
    const float4 bia = *reinterpret_cast<const float4*>(bias + col0 + tx * 4);
#pragma unroll
    for (int i = 0; i < 4; ++i) {
        ep[i * 1024 + (tx * 4 + 0) * 16 + ty] = f2bf(acc[i][0] + bia.x);
        ep[i * 1024 + (tx * 4 + 1) * 16 + ty] = f2bf(acc[i][1] + bia.y);
        ep[i * 1024 + (tx * 4 + 2) * 16 + ty] = f2bf(acc[i][2] + bia.z);
        ep[i * 1024 + (tx * 4 + 3) * 16 + ty] = f2bf(acc[i][3] + bia.w);
    }
    __syncthreads();

    const uint4* eps = (const uint4*)ep;
#pragma unroll
    for (int it = 0; it < 2; ++it) {
        const int idx = it * 256 + tid;   // 0..511 uint4s (4096 u16)
        const int ti  = idx >> 7;
        const int off = idx & 127;
        ushort_t* dst = x5 +
            ((((size_t)(t0 + ti) * 4 + bg) * 3 + g) * 256 + col0) * 16 + off * 8;
        *reinterpret_cast<uint4*>(dst) = eps[idx];
    }
}

// ---------------------------------------------------------------------------
// Kernel 2: recurrence, MFMA formulation.
// 4 blocks (16 batches each) x 512 threads (8 waves). Wave w owns 32 hidden
// cols (two 16x16 tiles). Per step, per block: three 16x256x256 GEMMs =
// 48 mfma_f32_16x16x32_bf16 per wave.
//   A-frag (lane l): A[m=l&15][k=(l>>4)*8+i]  -> b128 from LDS row m
//   B-frag (lane l): B[k=(l>>4)*8+i][n=l&15]  -> preloaded W^T rows (192 VGPR)
//   D      (lane l): D[m=(l>>4)*4+r][n=l&15]  (verified layout)
// H and R*H live in LDS [16][264] bf16 (8-u16 row pad -> 2-way banks on the
// stride-528B column reads). x[t] double-buffered in LDS via global_load_lds;
// raw s_barrier + explicit vmcnt(0) once per step (no per-step store drain).
// ---------------------------------------------------------------------------
#define LDSROW 264  // u16 per row: 256 + 8 pad

__global__ __launch_bounds__(512, 2) void gru_recur(
    const ushort_t* __restrict__ x5,   // [t][bg][g][j][b16] bf16
    const ushort_t* __restrict__ Tz, const ushort_t* __restrict__ Tr,
    const ushort_t* __restrict__ Th,
    float* __restrict__ out)           // [B][T][256] then H_last [B][256]
{
    __shared__ __align__(16) ushort_t Hl[16 * LDSROW];
    __shared__ __align__(16) ushort_t Rl[16 * LDSROW];
    __shared__ __align__(16) ushort_t Xb[2][12288];  // 2 x 24KB

    const int tid  = threadIdx.x;
    const int lane = tid & 63;
    const int w    = tid >> 6;    // wave 0..7
    const int kq   = lane >> 4;   // k-quadrant for A/B frags; D row group
    const int ml   = lane & 15;   // A row (batch) / D col (within tile)
    const int bg   = blockIdx.x;  // batch group 0..3

    // ---- all three W^T in VGPRs: 3 x 2 tiles x 8 ktiles x 4 regs = 192 ----
    sh8 wz[2][8], wr[2][8], wh[2][8];
#pragma unroll
    for (int c = 0; c < 2; ++c) {
        const int j = w * 32 + c * 16 + ml;
        const size_t rb = (size_t)j * 256 + kq * 8;
#pragma unroll
        for (int kt = 0; kt < 8; ++kt) {
            wz[c][kt] = *reinterpret_cast<const sh8*>(Tz + rb + kt * 32);
            wr[c][kt] = *reinterpret_cast<const sh8*>(Tr + rb + kt * 32);
            wh[c][kt] = *reinterpret_cast<const sh8*>(Th + rb + kt * 32);
        }
    }

    // zero H (incl. pad)
    for (int i = tid; i < 16 * LDSROW / 2; i += 512) ((uint_t*)Hl)[i] = 0u;

    float hk[2][4];  // fp32 H at this lane's D positions
#pragma unroll
    for (int c = 0; c < 2; ++c)
#pragma unroll
        for (int r = 0; r < 4; ++r) hk[c][r] = 0.f;

    // stage x[0]
    {
        const ushort_t* gsrc = x5 + (size_t)bg * 12288;
#pragma unroll
        for (int rd = 0; rd < 3; ++rd) {
            const int off = rd * 4096 + w * 512 + lane * 8;  // u16 units
            async_g2l(gsrc + off, &Xb[0][off]);
        }
    }
    asm volatile("s_waitcnt vmcnt(0)" ::: "memory");
    __syncthreads();

    const ushort_t* harow = Hl + ml * LDSROW + kq * 8;
    const ushort_t* rarow = Rl + ml * LDSROW + kq * 8;
    float* ob = out + (size_t)bg * 16 * TT * HD;

    int cur = 0;
    for (int t = 0; t < TT; ++t) {
        // issue async staging of x[t+1] into the other buffer
        {
            const int tn = (t < TT - 1) ? t + 1 : t;
            const ushort_t* gsrc = x5 + ((size_t)tn * 4 + bg) * 12288;
            ushort_t* l = Xb[cur ^ 1];
#pragma unroll
            for (int rd = 0; rd < 3; ++rd) {
                const int off = rd * 4096 + w * 512 + lane * 8;
                async_g2l(gsrc + off, l + off);
            }
        }
        const ushort_t* xc = Xb[cur];

        // ---- phase 1: Z, R = sigmoid(x + H @ W) ----
        fx4 az[2], ar[2];
        const fx4 zero4 = {0.f, 0.f, 0.f, 0.f};
        az[0] = zero4; az[1] = zero4; ar[0] = zero4; ar[1] = zero4;
#pragma unroll
        for (int kt = 0; kt < 8; ++kt) {
            const sh8 a = *reinterpret_cast<const sh8*>(harow + kt * 32);
            az[0] = mfma16(a, wz[0][kt], az[0]);
            az[1] = mfma16(a, wz[1][kt], az[1]);
            ar[0] = mfma16(a, wr[0][kt], ar[0]);
            ar[1] = mfma16(a, wr[1][kt], ar[1]);
        }
        float zf[2][4];
#pragma unroll
        for (int c = 0; c < 2; ++c) {
            const int j = w * 32 + c * 16 + ml;
            const uint2 xzv = *reinterpret_cast<const uint2*>(xc + j * 16 + kq * 4);
            const uint2 xrv = *reinterpret_cast<const uint2*>(xc + 4096 + j * 16 + kq * 4);
            const ushort_t* pxz = (const ushort_t*)&xzv;
            const ushort_t* pxr = (const ushort_t*)&xrv;
#pragma unroll
            for (int r = 0; r < 4; ++r) {
                const float z  = sigm(bf2f(pxz[r]) + az[c][r]);
                const float rr = sigm(bf2f(pxr[r]) + ar[c][r]);
                zf[c][r] = z;
                Rl[(kq * 4 + r) * LDSROW + j] = f2bf(rr * hk[c][r]);
            }
        }
        BAR();  // R*H visible to all waves

        // ---- phase 2: H~ = tanh(xh + (R*H) @ Whh); blend ----
        fx4 ah[2];
        ah[0] = zero4; ah[1] = zero4;
#pragma unroll
        for (int kt = 0; kt < 8; ++kt) {
            const sh8 a = *reinterpret_cast<const sh8*>(rarow + kt * 32);
            ah[0] = mfma16(a, wh[0][kt], ah[0]);
            ah[1] = mfma16(a, wh[1][kt], ah[1]);
        }
#pragma unroll
        for (int c = 0; c < 2; ++c) {
            const int j = w * 32 + c * 16 + ml;
            const uint2 xhv = *reinterpret_cast<const uint2*>(xc + 8192 + j * 16 + kq * 4);
            const ushort_t* pxh = (const ushort_t*)&xhv;
#pragma unroll
            for (int r = 0; r < 4; ++r) {
                const float th = tanh_fast(bf2f(pxh[r]) + ah[c][r]);
                const float hn = zf[c][r] * hk[c][r] + (1.f - zf[c][r]) * th;
                hk[c][r] = hn;
                Hl[(kq * 4 + r) * LDSROW + j] = f2bf(hn);
            }
        }
        asm volatile("s_waitcnt vmcnt(0)" ::: "memory");  // x[t+1] staged
        BAR();  // H + x-buffer safe for next step

        // out[t] stores AFTER the barrier: fire-and-forget, drained by the
        // NEXT iteration's vmcnt(0) (a full step later -> no stall)
#pragma unroll
        for (int c = 0; c < 2; ++c) {
            const int j = w * 32 + c * 16 + ml;
#pragma unroll
            for (int r = 0; r < 4; ++r)
                ob[((size_t)(kq * 4 + r) * TT + t) * HD + j] = hk[c][r];
        }
        cur ^= 1;
    }

    // H_last
    float* hl = out + (size_t)BB * TT * HD + (size_t)bg * 16 * HD;
#pragma unroll
    for (int c = 0; c < 2; ++c) {
        const int j = w * 32 + c * 16 + ml;
#pragma unroll
        for (int r = 0; r < 4; ++r)
            hl[(kq * 4 + r) * HD + j] = hk[c][r];
    }
}

// ---------------------------------------------------------------------------
extern "C" void kernel_launch(void* const* d_in, const int* in_sizes, int n_in,
                              void* d_out, int out_size, void* d_ws, size_t ws_size,
                              hipStream_t stream) {
    const float* X   = (const float*)d_in[0];
    const float* Wxz = (const float*)d_in[1];
    const float* Whz = (const float*)d_in[2];
    const float* bz  = (const float*)d_in[3];
    const float* Wxr = (const float*)d_in[4];
    const float* Whr = (const float*)d_in[5];
    const float* br  = (const float*)d_in[6];
    const float* Wxh = (const float*)d_in[7];
    const float* Whh = (const float*)d_in[8];
    const float* bh  = (const float*)d_in[9];
    float* out = (float*)d_out;

    // ws layout: [0, 96 MiB) x5 bf16 [t][bg][g][j][b16]; then 3 x 128 KiB W^T
    const size_t X5_BYTES = (size_t)TT * 4 * 3 * 256 * 16 * 2;
    ushort_t* x5 = (ushort_t*)d_ws;
    ushort_t* Tz = (ushort_t*)((char*)d_ws + X5_BYTES);
    ushort_t* Tr = Tz + HD * HD;
    ushort_t* Th = Tr + HD * HD;

    prepack_kernel<<<dim3(256, 3), 256, 0, stream>>>(Whz, Whr, Whh, Tz, Tr, Th);
    proj_kernel<<<dim3(1024, 12), 256, 0, stream>>>(X, Wxz, Wxr, Wxh, bz, br, bh, x5);
    gru_recur<<<dim3(4), 512, 0, stream>>>(x5, Tz, Tr, Th, out);
}

// Round 3
// 2274.233 us; speedup vs baseline: 1.1707x; 1.1707x over previous
//
#include <hip/hip_runtime.h>
#include <math.h>

#define BB 64
#define TT 1024
#define II 256
#define HD 256

typedef unsigned short ushort_t;
typedef unsigned int uint_t;

// MFMA fragment types
typedef short sh8 __attribute__((ext_vector_type(8)));
typedef float fx4 __attribute__((ext_vector_type(4)));

// ---- bf16 helpers (manual, RNE) -------------------------------------------
__device__ __forceinline__ ushort_t f2bf(float f) {
    uint_t u = __float_as_uint(f);
    uint_t r = (u + 0x7fffu + ((u >> 16) & 1u)) >> 16;
    return (ushort_t)r;
}
__device__ __forceinline__ float bf2f(ushort_t v) {
    return __uint_as_float(((uint_t)v) << 16);
}

__device__ __forceinline__ float fast_rcp(float x) {
#if __has_builtin(__builtin_amdgcn_rcpf)
    return __builtin_amdgcn_rcpf(x);
#else
    return 1.f / x;
#endif
}
__device__ __forceinline__ float sigm(float x) {
    return fast_rcp(1.f + __expf(-x));
}
__device__ __forceinline__ float tanh_fast(float x) {
    return 1.f - 2.f * fast_rcp(1.f + __expf(2.f * x));
}

__device__ __forceinline__ fx4 mfma16(sh8 a, sh8 b, fx4 c) {
    return __builtin_amdgcn_mfma_f32_16x16x32_bf16(a, b, c, 0, 0, 0);
}

// async global->LDS, 16B per lane (per-lane gptr; LDS dst = wave base + lane*16)
__device__ __forceinline__ void async_g2l(const ushort_t* g, ushort_t* l) {
#if __has_builtin(__builtin_amdgcn_global_load_lds)
    __builtin_amdgcn_global_load_lds(
        (const __attribute__((address_space(1))) unsigned int*)g,
        (__attribute__((address_space(3))) unsigned int*)l, 16, 0, 0);
#else
    *reinterpret_cast<uint4*>(l) = *reinterpret_cast<const uint4*>(g);
#endif
}

// raw barrier: drain LDS ops only; vmcnt waited explicitly where needed
#define BAR() asm volatile("s_waitcnt lgkmcnt(0)\n\ts_barrier" ::: "memory")

// ---------------------------------------------------------------------------
// Kernel 0: prepack recurrent weights fp32 W[k][j] -> bf16 W^T:  T[j*256+k]
// ---------------------------------------------------------------------------
__global__ __launch_bounds__(256) void prepack_kernel(
    const float* __restrict__ Wz, const float* __restrict__ Wr,
    const float* __restrict__ Wh,
    ushort_t* __restrict__ Tz, ushort_t* __restrict__ Tr,
    ushort_t* __restrict__ Th)
{
    const int idx = blockIdx.x * 256 + threadIdx.x;  // 0..65535
    const int j = idx >> 8;
    const int k = idx & 255;
    const float* W = (blockIdx.y == 0) ? Wz : (blockIdx.y == 1) ? Wr : Wh;
    ushort_t* T = (blockIdx.y == 0) ? Tz : (blockIdx.y == 1) ? Tr : Th;
    T[idx] = f2bf(W[k * HD + j]);
}

// ---------------------------------------------------------------------------
// Kernel 1: input projection GEMM -> bf16 x5[t][bg8][g][j][b8]
// Block = 8 batches (bg8) x 8 timesteps x 64 cols of one gate g.
// Epilogue stages [ti][j][bi] in LDS then writes 1KB-contiguous runs.
// ---------------------------------------------------------------------------
__global__ __launch_bounds__(256) void proj_kernel(
    const float* __restrict__ X,
    const float* __restrict__ Wz, const float* __restrict__ Wr,
    const float* __restrict__ Wh,
    const float* __restrict__ bz, const float* __restrict__ br,
    const float* __restrict__ bh,
    ushort_t* __restrict__ x5)
{
    __shared__ float As[64][36];
    __shared__ float Bs[32][64];
    __shared__ ushort_t ep[8 * 64 * 8];  // [ti(8)][j(64)][bi(8)] = 8KB

    const int tid  = threadIdx.x;
    const int tx   = tid & 15;
    const int ty   = tid >> 4;
    const int bg8  = blockIdx.x >> 7;          // batch group 0..7 (8 batches)
    const int t0   = (blockIdx.x & 127) * 8;   // timestep base
    const int g    = blockIdx.y >> 2;
    const int col0 = (blockIdx.y & 3) * 64;

    const float* W    = (g == 0) ? Wz : (g == 1) ? Wr : Wh;
    const float* bias = (g == 0) ? bz : (g == 1) ? br : bh;

    float acc[4][4];
#pragma unroll
    for (int i = 0; i < 4; ++i)
#pragma unroll
        for (int j = 0; j < 4; ++j) acc[i][j] = 0.f;

    for (int k0 = 0; k0 < II; k0 += 32) {
        int fi = tid;
#pragma unroll
        for (int rp = 0; rp < 2; ++rp, fi += 256) {
            const int row = fi >> 3;       // 0..63: bi = row>>3, ti = row&7
            const int fc  = fi & 7;
            const size_t m = (size_t)(bg8 * 8 + (row >> 3)) * 1024 + t0 + (row & 7);
            const float4 v = *reinterpret_cast<const float4*>(
                X + m * II + k0 + fc * 4);
            *reinterpret_cast<float4*>(&As[row][fc * 4]) = v;
        }
        fi = tid;
#pragma unroll
        for (int rp = 0; rp < 2; ++rp, fi += 256) {
            const int row = fi >> 4;
            const int fc  = fi & 15;
            const float4 v = *reinterpret_cast<const float4*>(
                W + (size_t)(k0 + row) * HD + col0 + fc * 4);
            *reinterpret_cast<float4*>(&Bs[row][fc * 4]) = v;
        }
        __syncthreads();

#pragma unroll
        for (int kk = 0; kk < 32; ++kk) {
            const float a0 = As[ty * 4 + 0][kk];
            const float a1 = As[ty * 4 + 1][kk];
            const float a2 = As[ty * 4 + 2][kk];
            const float a3 = As[ty * 4 + 3][kk];
            const float4 bv = *reinterpret_cast<const float4*>(&Bs[kk][tx * 4]);
            acc[0][0] += a0 * bv.x; acc[0][1] += a0 * bv.y;
            acc[0][2] += a0 * bv.z; acc[0][3] += a0 * bv.w;
            acc[1][0] += a1 * bv.x; acc[1][1] += a1 * bv.y;
            acc[1][2] += a1 * bv.z; acc[1][3] += a1 * bv.w;
            acc[2][0] += a2 * bv.x; acc[2][1] += a2 * bv.y;
            acc[2][2] += a2 * bv.z; acc[2][3] += a2 * bv.w;
            acc[3][0] += a3 * bv.x; acc[3][1] += a3 * bv.y;
            acc[3][2] += a3 * bv.z; acc[3][3] += a3 * bv.w;
        }
        __syncthreads();
    }

    // thread (tx,ty) holds rows r=ty*4+i (bi=r>>3, ti=r&7); cols col0+tx*4+jj
    const float4 bia = *reinterpret_cast<const float4*>(bias + col0 + tx * 4);
#pragma unroll
    for (int i = 0; i < 4; ++i) {
        const int rr = ty * 4 + i;
        const int bi = rr >> 3;
        const int ti = rr & 7;
        ep[ti * 512 + (tx * 4 + 0) * 8 + bi] = f2bf(acc[i][0] + bia.x);
        ep[ti * 512 + (tx * 4 + 1) * 8 + bi] = f2bf(acc[i][1] + bia.y);
        ep[ti * 512 + (tx * 4 + 2) * 8 + bi] = f2bf(acc[i][2] + bia.z);
        ep[ti * 512 + (tx * 4 + 3) * 8 + bi] = f2bf(acc[i][3] + bia.w);
    }
    __syncthreads();

    const uint4* eps = (const uint4*)ep;
#pragma unroll
    for (int it = 0; it < 2; ++it) {
        const int idx = it * 256 + tid;   // 0..511 uint4s (4096 u16)
        const int ti  = idx >> 6;
        const int off = idx & 63;         // j-local
        ushort_t* dst = x5 +
            ((((size_t)(t0 + ti) * 8 + bg8) * 3 + g) * 256 + col0 + off) * 8;
        *reinterpret_cast<uint4*>(dst) = eps[idx];
    }
}

// ---------------------------------------------------------------------------
// Kernel 2: recurrence, MFMA, 8 blocks x 8 batches (M=8, rows 8-15 = dup).
// 512 threads (8 waves); wave owns 32 cols (2 tiles). Per step per block:
// 384 mfma_16x16x32_bf16 (48/wave).
//   A-frag: lane l reads H row (l&7)  -> same-address broadcast halves LDS BW
//   B-frag: preloaded W^T (192 VGPRs/thread)
//   D rows 0-7 valid; epilogue packed via shfl_xor(.,32): lane (kq,ml) owns
//   tile c=kq>>1, rows q*4+r (q=kq&1), col j=w*32+c*16+ml -> 4 els/lane,
//   zero masked-idle VALU. x5 staged [g][j][b8] -> b64 reads per gate.
// ---------------------------------------------------------------------------
#define LDSROW 264  // u16 per row: 256 + 8 pad (row stride 528B)
#define XB_U16 6144 // 3*256*8 per (t,bg)

__global__ __launch_bounds__(512, 2) void gru_recur(
    const ushort_t* __restrict__ x5,   // [t][bg8][g][j][b8] bf16
    const ushort_t* __restrict__ Tz, const ushort_t* __restrict__ Tr,
    const ushort_t* __restrict__ Th,
    float* __restrict__ out)           // [B][T][256] then H_last [B][256]
{
    __shared__ __align__(16) ushort_t Hl[8 * LDSROW];
    __shared__ __align__(16) ushort_t Rl[8 * LDSROW];
    __shared__ __align__(16) ushort_t Xb[2][XB_U16];

    const int tid  = threadIdx.x;
    const int lane = tid & 63;
    const int w    = tid >> 6;    // wave 0..7
    const int kq   = lane >> 4;   // frag k-quadrant / D row group
    const int ml   = lane & 15;   // A row (dup of &7) / D col
    const int mr   = lane & 7;    // batch row for A reads
    const int q    = kq & 1;      // packed: row-half (batches q*4+r)
    const int c    = kq >> 1;     // packed: column tile
    const int jp   = w * 32 + c * 16 + ml;  // packed hidden col
    const int bg   = blockIdx.x;  // batch group 0..7 (8 batches)

    // ---- all three W^T in VGPRs: 3 x 2 tiles x 8 ktiles x 4 regs = 192 ----
    sh8 wz[2][8], wr[2][8], wh[2][8];
#pragma unroll
    for (int cc = 0; cc < 2; ++cc) {
        const int j = w * 32 + cc * 16 + ml;
        const size_t rb = (size_t)j * 256 + kq * 8;
#pragma unroll
        for (int kt = 0; kt < 8; ++kt) {
            wz[cc][kt] = *reinterpret_cast<const sh8*>(Tz + rb + kt * 32);
            wr[cc][kt] = *reinterpret_cast<const sh8*>(Tr + rb + kt * 32);
            wh[cc][kt] = *reinterpret_cast<const sh8*>(Th + rb + kt * 32);
        }
    }

    // zero H (incl. pad): 8*264 u16 = 1056 u32
    for (int i = tid; i < 8 * LDSROW / 2; i += 512) ((uint_t*)Hl)[i] = 0u;

    float hk[4];  // packed H: hk[r] = H[bg*8 + q*4 + r][jp]
#pragma unroll
    for (int r = 0; r < 4; ++r) hk[r] = 0.f;

    // stage x[0]: 12288 B = 512*16 + 256*16
    {
        const ushort_t* gsrc = x5 + (size_t)bg * XB_U16;
        async_g2l(gsrc + tid * 8, &Xb[0][tid * 8]);
        if (tid < 256) async_g2l(gsrc + 4096 + tid * 8, &Xb[0][4096 + tid * 8]);
    }
    asm volatile("s_waitcnt vmcnt(0)" ::: "memory");
    __syncthreads();

    const ushort_t* harow = Hl + mr * LDSROW + kq * 8;
    const ushort_t* rarow = Rl + mr * LDSROW + kq * 8;
    float* ob = out + (size_t)bg * 8 * TT * HD;

    int cur = 0;
    for (int t = 0; t < TT; ++t) {
        // issue async staging of x[t+1] into the other buffer
        {
            const int tn = (t < TT - 1) ? t + 1 : t;
            const ushort_t* gsrc = x5 + ((size_t)tn * 8 + bg) * XB_U16;
            ushort_t* l = Xb[cur ^ 1];
            async_g2l(gsrc + tid * 8, l + tid * 8);
            if (tid < 256) async_g2l(gsrc + 4096 + tid * 8, l + 4096 + tid * 8);
        }
        const ushort_t* xc = Xb[cur];

        // ---- phase 1: Z, R = sigmoid(x + H @ W) ----
        fx4 az[2], ar[2];
        const fx4 zero4 = {0.f, 0.f, 0.f, 0.f};
        az[0] = zero4; az[1] = zero4; ar[0] = zero4; ar[1] = zero4;
#pragma unroll
        for (int kt = 0; kt < 8; ++kt) {
            const sh8 a = *reinterpret_cast<const sh8*>(harow + kt * 32);
            az[0] = mfma16(a, wz[0][kt], az[0]);
            az[1] = mfma16(a, wz[1][kt], az[1]);
            ar[0] = mfma16(a, wr[0][kt], ar[0]);
            ar[1] = mfma16(a, wr[1][kt], ar[1]);
        }
        // pack: lane (kq,ml) takes tile c=kq>>1, rows q*4+r from lane^ (c*32)
        float zf[4];
        {
            const ushort4 xzv = *reinterpret_cast<const ushort4*>(
                xc + (size_t)jp * 8 + q * 4);
            const ushort4 xrv = *reinterpret_cast<const ushort4*>(
                xc + 2048 + (size_t)jp * 8 + q * 4);
            const ushort_t* pxz = (const ushort_t*)&xzv;
            const ushort_t* pxr = (const ushort_t*)&xrv;
#pragma unroll
            for (int r = 0; r < 4; ++r) {
                const float tz = __shfl_xor(az[1][r], 32);
                const float tr = __shfl_xor(ar[1][r], 32);
                const float pz = (lane < 32) ? az[0][r] : tz;
                const float pr = (lane < 32) ? ar[0][r] : tr;
                const float z  = sigm(bf2f(pxz[r]) + pz);
                const float rr = sigm(bf2f(pxr[r]) + pr);
                zf[r] = z;
                Rl[(q * 4 + r) * LDSROW + jp] = f2bf(rr * hk[r]);
            }
        }
        BAR();  // R*H visible to all waves

        // ---- phase 2: H~ = tanh(xh + (R*H) @ Whh); blend ----
        fx4 ah[2];
        ah[0] = zero4; ah[1] = zero4;
#pragma unroll
        for (int kt = 0; kt < 8; ++kt) {
            const sh8 a = *reinterpret_cast<const sh8*>(rarow + kt * 32);
            ah[0] = mfma16(a, wh[0][kt], ah[0]);
            ah[1] = mfma16(a, wh[1][kt], ah[1]);
        }
        {
            const ushort4 xhv = *reinterpret_cast<const ushort4*>(
                xc + 4096 + (size_t)jp * 8 + q * 4);
            const ushort_t* pxh = (const ushort_t*)&xhv;
#pragma unroll
            for (int r = 0; r < 4; ++r) {
                const float th0 = __shfl_xor(ah[1][r], 32);
                const float ph  = (lane < 32) ? ah[0][r] : th0;
                const float th  = tanh_fast(bf2f(pxh[r]) + ph);
                const float hn  = zf[r] * hk[r] + (1.f - zf[r]) * th;
                hk[r] = hn;
                Hl[(q * 4 + r) * LDSROW + jp] = f2bf(hn);
            }
        }
        asm volatile("s_waitcnt vmcnt(0)" ::: "memory");  // x[t+1] staged
        BAR();  // H + x-buffer safe for next step

        // out stores after the barrier: fire-and-forget, drained by the NEXT
        // iteration's vmcnt(0) (a full step later)
#pragma unroll
        for (int r = 0; r < 4; ++r)
            ob[((size_t)(q * 4 + r) * TT + t) * HD + jp] = hk[r];
        cur ^= 1;
    }

    // H_last
#pragma unroll
    for (int r = 0; r < 4; ++r)
        out[(size_t)BB * TT * HD + (size_t)(bg * 8 + q * 4 + r) * HD + jp] = hk[r];
}

// ---------------------------------------------------------------------------
extern "C" void kernel_launch(void* const* d_in, const int* in_sizes, int n_in,
                              void* d_out, int out_size, void* d_ws, size_t ws_size,
                              hipStream_t stream) {
    const float* X   = (const float*)d_in[0];
    const float* Wxz = (const float*)d_in[1];
    const float* Whz = (const float*)d_in[2];
    const float* bz  = (const float*)d_in[3];
    const float* Wxr = (const float*)d_in[4];
    const float* Whr = (const float*)d_in[5];
    const float* br  = (const float*)d_in[6];
    const float* Wxh = (const float*)d_in[7];
    const float* Whh = (const float*)d_in[8];
    const float* bh  = (const float*)d_in[9];
    float* out = (float*)d_out;

    // ws layout: [0, 96 MiB) x5 bf16 [t][bg8][g][j][b8]; then 3 x 128 KiB W^T
    const size_t X5_BYTES = (size_t)TT * 8 * 3 * 256 * 8 * 2;
    ushort_t* x5 = (ushort_t*)d_ws;
    ushort_t* Tz = (ushort_t*)((char*)d_ws + X5_BYTES);
    ushort_t* Tr = Tz + HD * HD;
    ushort_t* Th = Tr + HD * HD;

    prepack_kernel<<<dim3(256, 3), 256, 0, stream>>>(Whz, Whr, Whh, Tz, Tr, Th);
    proj_kernel<<<dim3(1024, 12), 256, 0, stream>>>(X, Wxz, Wxr, Wxh, bz, br, bh, x5);
    gru_recur<<<dim3(8), 512, 0, stream>>>(x5, Tz, Tr, Th, out);
}

// Round 4
// 1560.477 us; speedup vs baseline: 1.7062x; 1.4574x over previous
//
#include <hip/hip_runtime.h>
#include <math.h>

#define BB 64
#define TT 1024
#define II 256
#define HD 256

typedef unsigned short ushort_t;
typedef unsigned int uint_t;

// MFMA fragment types
typedef short sh8 __attribute__((ext_vector_type(8)));
typedef float fx4 __attribute__((ext_vector_type(4)));

// ---- bf16 helpers (manual, RNE) -------------------------------------------
__device__ __forceinline__ ushort_t f2bf(float f) {
    uint_t u = __float_as_uint(f);
    uint_t r = (u + 0x7fffu + ((u >> 16) & 1u)) >> 16;
    return (ushort_t)r;
}
__device__ __forceinline__ float bf2f(ushort_t v) {
    return __uint_as_float(((uint_t)v) << 16);
}

__device__ __forceinline__ float fast_rcp(float x) {
#if __has_builtin(__builtin_amdgcn_rcpf)
    return __builtin_amdgcn_rcpf(x);
#else
    return 1.f / x;
#endif
}
__device__ __forceinline__ float sigm(float x) {
    return fast_rcp(1.f + __expf(-x));
}
__device__ __forceinline__ float tanh_fast(float x) {
    return 1.f - 2.f * fast_rcp(1.f + __expf(2.f * x));
}

__device__ __forceinline__ fx4 mfma16(sh8 a, sh8 b, fx4 c) {
    return __builtin_amdgcn_mfma_f32_16x16x32_bf16(a, b, c, 0, 0, 0);
}

// async global->LDS, 16B per lane (per-lane gptr; LDS dst = wave base + lane*16)
__device__ __forceinline__ void async_g2l(const ushort_t* g, ushort_t* l) {
#if __has_builtin(__builtin_amdgcn_global_load_lds)
    __builtin_amdgcn_global_load_lds(
        (const __attribute__((address_space(1))) unsigned int*)g,
        (__attribute__((address_space(3))) unsigned int*)l, 16, 0, 0);
#else
    *reinterpret_cast<uint4*>(l) = *reinterpret_cast<const uint4*>(g);
#endif
}

// raw barrier: drain LDS ops only; vmcnt waited explicitly where needed
#define BAR() asm volatile("s_waitcnt lgkmcnt(0)\n\ts_barrier" ::: "memory")

// ---------------------------------------------------------------------------
// Kernel 0: prepack recurrent weights fp32 W[k][j] -> bf16 W^T:  T[j*256+k]
// ---------------------------------------------------------------------------
__global__ __launch_bounds__(256) void prepack_kernel(
    const float* __restrict__ Wz, const float* __restrict__ Wr,
    const float* __restrict__ Wh,
    ushort_t* __restrict__ Tz, ushort_t* __restrict__ Tr,
    ushort_t* __restrict__ Th)
{
    const int idx = blockIdx.x * 256 + threadIdx.x;  // 0..65535
    const int j = idx >> 8;
    const int k = idx & 255;
    const float* W = (blockIdx.y == 0) ? Wz : (blockIdx.y == 1) ? Wr : Wh;
    ushort_t* T = (blockIdx.y == 0) ? Tz : (blockIdx.y == 1) ? Tr : Th;
    T[idx] = f2bf(W[k * HD + j]);
}

// ---------------------------------------------------------------------------
// Kernel 1: input projection GEMM -> bf16 x5[t][b][g][j]
// Block = 8 batches x 8 timesteps x 64 cols of one gate g.
// Epilogue stages [ti][bi][j(64)] in LDS then writes 128B-contiguous runs.
// ---------------------------------------------------------------------------
__global__ __launch_bounds__(256) void proj_kernel(
    const float* __restrict__ X,
    const float* __restrict__ Wz, const float* __restrict__ Wr,
    const float* __restrict__ Wh,
    const float* __restrict__ bz, const float* __restrict__ br,
    const float* __restrict__ bh,
    ushort_t* __restrict__ x5)
{
    __shared__ float As[64][36];
    __shared__ float Bs[32][64];
    __shared__ ushort_t ep[8 * 8 * 64];  // [ti(8)][bi(8)][j(64)] = 8KB

    const int tid  = threadIdx.x;
    const int tx   = tid & 15;
    const int ty   = tid >> 4;
    const int bg8  = blockIdx.x >> 7;          // batch group 0..7 (8 batches)
    const int t0   = (blockIdx.x & 127) * 8;   // timestep base
    const int g    = blockIdx.y >> 2;
    const int col0 = (blockIdx.y & 3) * 64;

    const float* W    = (g == 0) ? Wz : (g == 1) ? Wr : Wh;
    const float* bias = (g == 0) ? bz : (g == 1) ? br : bh;

    float acc[4][4];
#pragma unroll
    for (int i = 0; i < 4; ++i)
#pragma unroll
        for (int j = 0; j < 4; ++j) acc[i][j] = 0.f;

    for (int k0 = 0; k0 < II; k0 += 32) {
        int fi = tid;
#pragma unroll
        for (int rp = 0; rp < 2; ++rp, fi += 256) {
            const int row = fi >> 3;       // 0..63: bi = row>>3, ti = row&7
            const int fc  = fi & 7;
            const size_t m = (size_t)(bg8 * 8 + (row >> 3)) * 1024 + t0 + (row & 7);
            const float4 v = *reinterpret_cast<const float4*>(
                X + m * II + k0 + fc * 4);
            *reinterpret_cast<float4*>(&As[row][fc * 4]) = v;
        }
        fi = tid;
#pragma unroll
        for (int rp = 0; rp < 2; ++rp, fi += 256) {
            const int row = fi >> 4;
            const int fc  = fi & 15;
            const float4 v = *reinterpret_cast<const float4*>(
                W + (size_t)(k0 + row) * HD + col0 + fc * 4);
            *reinterpret_cast<float4*>(&Bs[row][fc * 4]) = v;
        }
        __syncthreads();

#pragma unroll
        for (int kk = 0; kk < 32; ++kk) {
            const float a0 = As[ty * 4 + 0][kk];
            const float a1 = As[ty * 4 + 1][kk];
            const float a2 = As[ty * 4 + 2][kk];
            const float a3 = As[ty * 4 + 3][kk];
            const float4 bv = *reinterpret_cast<const float4*>(&Bs[kk][tx * 4]);
            acc[0][0] += a0 * bv.x; acc[0][1] += a0 * bv.y;
            acc[0][2] += a0 * bv.z; acc[0][3] += a0 * bv.w;
            acc[1][0] += a1 * bv.x; acc[1][1] += a1 * bv.y;
            acc[1][2] += a1 * bv.z; acc[1][3] += a1 * bv.w;
            acc[2][0] += a2 * bv.x; acc[2][1] += a2 * bv.y;
            acc[2][2] += a2 * bv.z; acc[2][3] += a2 * bv.w;
            acc[3][0] += a3 * bv.x; acc[3][1] += a3 * bv.y;
            acc[3][2] += a3 * bv.z; acc[3][3] += a3 * bv.w;
        }
        __syncthreads();
    }

    // thread (tx,ty) holds rows r=ty*4+i (bi=r>>3, ti=r&7); cols col0+tx*4+jj
    const float4 bia = *reinterpret_cast<const float4*>(bias + col0 + tx * 4);
#pragma unroll
    for (int i = 0; i < 4; ++i) {
        const int rr = ty * 4 + i;
        const int bi = rr >> 3;
        const int ti = rr & 7;
        ep[ti * 512 + bi * 64 + tx * 4 + 0] = f2bf(acc[i][0] + bia.x);
        ep[ti * 512 + bi * 64 + tx * 4 + 1] = f2bf(acc[i][1] + bia.y);
        ep[ti * 512 + bi * 64 + tx * 4 + 2] = f2bf(acc[i][2] + bia.z);
        ep[ti * 512 + bi * 64 + tx * 4 + 3] = f2bf(acc[i][3] + bia.w);
    }
    __syncthreads();

    const uint4* eps = (const uint4*)ep;
#pragma unroll
    for (int it = 0; it < 2; ++it) {
        const int idx  = it * 256 + tid;   // 0..511 uint4s (4096 u16)
        const int ti   = idx >> 6;
        const int bi   = (idx >> 3) & 7;
        const int part = idx & 7;
        ushort_t* dst = x5 +
            (((size_t)(t0 + ti) * 64 + (bg8 * 8 + bi)) * 3 + g) * 256 +
            col0 + part * 8;
        *reinterpret_cast<uint4*>(dst) = eps[idx];
    }
}

// ---------------------------------------------------------------------------
// Kernel 2: recurrence, MFMA, 64 blocks x 1 batch. 512 threads (8 waves);
// wave owns 32 cols (2 tiles). 48 mfma/wave/step (M=1, rows 1-15 = dup).
//   A-frag: ALL lanes read the single H row at (kq*8 + kt*32) -> 16-lane
//   same-address broadcast per 16B slot, 16 disjoint banks -> conflict-free.
//   Degeneracy: with duplicated A rows, EVERY lane's acc reg[0] holds
//   D[0][lane&15] -> epilogue needs no shuffles. Lane duty: gate=lane>>5
//   (0:z, 1:r), col=w*32+(lane&31); phase2 lanes<32 do tanh+blend.
//   x[t] double-buffered in LDS (768 u16/step, 96-lane async stage).
// ---------------------------------------------------------------------------
#define XB_U16 768  // 3*256 per (t,b)

__global__ __launch_bounds__(512, 2) void gru_recur(
    const ushort_t* __restrict__ x5,   // [t][b][g][j] bf16
    const ushort_t* __restrict__ Tz, const ushort_t* __restrict__ Tr,
    const ushort_t* __restrict__ Th,
    float* __restrict__ out)           // [B][T][256] then H_last [B][256]
{
    __shared__ __align__(16) ushort_t Hl[264];
    __shared__ __align__(16) ushort_t Rl[264];
    __shared__ __align__(16) ushort_t Xb[2][XB_U16];

    const int tid  = threadIdx.x;
    const int lane = tid & 63;
    const int w    = tid >> 6;      // wave 0..7
    const int kq   = lane >> 4;     // frag k-quadrant
    const int ml   = lane & 15;     // frag position
    const int cl   = lane & 31;     // epilogue column within wave
    const int gate = lane >> 5;     // 0: z-duty, 1: r-duty
    const int sel  = (lane >> 4) & 1;  // which tile's acc reg
    const int j    = w * 32 + cl;   // hidden column this lane handles
    const int b    = blockIdx.x;    // batch 0..63

    // ---- all three W^T in VGPRs: 3 x 2 tiles x 8 ktiles x 4 regs = 192 ----
    sh8 wz[2][8], wr[2][8], wh[2][8];
#pragma unroll
    for (int cc = 0; cc < 2; ++cc) {
        const int jw = w * 32 + cc * 16 + ml;
        const size_t rb = (size_t)jw * 256 + kq * 8;
#pragma unroll
        for (int kt = 0; kt < 8; ++kt) {
            wz[cc][kt] = *reinterpret_cast<const sh8*>(Tz + rb + kt * 32);
            wr[cc][kt] = *reinterpret_cast<const sh8*>(Tr + rb + kt * 32);
            wh[cc][kt] = *reinterpret_cast<const sh8*>(Th + rb + kt * 32);
        }
    }

    // zero H/R rows (264 u16 = 132 u32 each)
    if (tid < 132) { ((uint_t*)Hl)[tid] = 0u; ((uint_t*)Rl)[tid] = 0u; }

    float hk = 0.f;  // lanes 0-31: H[b][j]; lanes 32-63 unused

    // stage x[0]: 768 u16 = 1536B = 96 lanes x 16B
    if (tid < 96) async_g2l(x5 + (size_t)b * XB_U16 + tid * 8, &Xb[0][tid * 8]);
    asm volatile("s_waitcnt vmcnt(0)" ::: "memory");
    __syncthreads();

    const ushort_t* harow = Hl + kq * 8;
    const ushort_t* rarow = Rl + kq * 8;
    float* ob = out + (size_t)b * TT * HD;

    const fx4 zero4 = {0.f, 0.f, 0.f, 0.f};
    int cur = 0;
    for (int t = 0; t < TT; ++t) {
        // issue async staging of x[t+1] into the other buffer
        {
            const int tn = (t < TT - 1) ? t + 1 : t;
            if (tid < 96)
                async_g2l(x5 + ((size_t)tn * 64 + b) * XB_U16 + tid * 8,
                          &Xb[cur ^ 1][tid * 8]);
        }
        const ushort_t* xc = Xb[cur];

        // ---- phase 1: Z, R = sigmoid(x + H @ W) ----
        fx4 az0 = zero4, az1 = zero4, ar0 = zero4, ar1 = zero4;
#pragma unroll
        for (int kt = 0; kt < 8; ++kt) {
            const sh8 a = *reinterpret_cast<const sh8*>(harow + kt * 32);
            az0 = mfma16(a, wz[0][kt], az0);
            az1 = mfma16(a, wz[1][kt], az1);
            ar0 = mfma16(a, wr[0][kt], ar0);
            ar1 = mfma16(a, wr[1][kt], ar1);
        }
        // every lane's reg[0] = D[0][lane&15] (A rows duplicated) -> no shfl
        const float v0 = gate ? ar0[0] : az0[0];
        const float v1 = gate ? ar1[0] : az1[0];
        const float v  = sel ? v1 : v0;
        const float xg = bf2f(xc[gate * 256 + j]);
        const float s  = sigm(xg + v);
        const float zreg = s;               // meaningful in lanes 0-31
        const float hsh  = __shfl(hk, cl);  // h[j] fetched into lanes 32-63
        if (gate) Rl[j] = f2bf(s * hsh);
        BAR();  // R*H visible to all waves

        // ---- phase 2: H~ = tanh(xh + (R*H) @ Whh); blend ----
        fx4 ah0 = zero4, ah1 = zero4;
#pragma unroll
        for (int kt = 0; kt < 8; ++kt) {
            const sh8 a = *reinterpret_cast<const sh8*>(rarow + kt * 32);
            ah0 = mfma16(a, wh[0][kt], ah0);
            ah1 = mfma16(a, wh[1][kt], ah1);
        }
        float hn = hk;
        if (!gate) {  // lanes 0-31 finish their column
            const float va = sel ? ah1[0] : ah0[0];
            const float xh = bf2f(xc[512 + j]);
            const float th = tanh_fast(xh + va);
            hn = zreg * hk + (1.f - zreg) * th;
            hk = hn;
            Hl[j] = f2bf(hn);
        }
        asm volatile("s_waitcnt vmcnt(0)" ::: "memory");  // x[t+1] staged
        BAR();  // H + x-buffer safe for next step

        // out store after the barrier (fire-and-forget; drained by the NEXT
        // iteration's vmcnt(0), a full step later)
        if (!gate) ob[(size_t)t * HD + j] = hn;
        cur ^= 1;
    }

    // H_last
    if (!gate) out[(size_t)BB * TT * HD + (size_t)b * HD + j] = hk;
}

// ---------------------------------------------------------------------------
extern "C" void kernel_launch(void* const* d_in, const int* in_sizes, int n_in,
                              void* d_out, int out_size, void* d_ws, size_t ws_size,
                              hipStream_t stream) {
    const float* X   = (const float*)d_in[0];
    const float* Wxz = (const float*)d_in[1];
    const float* Whz = (const float*)d_in[2];
    const float* bz  = (const float*)d_in[3];
    const float* Wxr = (const float*)d_in[4];
    const float* Whr = (const float*)d_in[5];
    const float* br  = (const float*)d_in[6];
    const float* Wxh = (const float*)d_in[7];
    const float* Whh = (const float*)d_in[8];
    const float* bh  = (const float*)d_in[9];
    float* out = (float*)d_out;

    // ws layout: [0, 96 MiB) x5 bf16 [t][b][g][j]; then 3 x 128 KiB W^T
    const size_t X5_BYTES = (size_t)TT * BB * 3 * 256 * 2;
    ushort_t* x5 = (ushort_t*)d_ws;
    ushort_t* Tz = (ushort_t*)((char*)d_ws + X5_BYTES);
    ushort_t* Tr = Tz + HD * HD;
    ushort_t* Th = Tr + HD * HD;

    prepack_kernel<<<dim3(256, 3), 256, 0, stream>>>(Whz, Whr, Whh, Tz, Tr, Th);
    proj_kernel<<<dim3(1024, 12), 256, 0, stream>>>(X, Wxz, Wxr, Wxh, bz, br, bh, x5);
    gru_recur<<<dim3(64), 512, 0, stream>>>(x5, Tz, Tr, Th, out);
}

// Round 5
// 1412.319 us; speedup vs baseline: 1.8851x; 1.1049x over previous
//
#include <hip/hip_runtime.h>
#include <math.h>

#define BB 64
#define TT 1024
#define II 256
#define HD 256

typedef unsigned short ushort_t;
typedef unsigned int uint_t;

// MFMA fragment types
typedef short sh8 __attribute__((ext_vector_type(8)));
typedef float fx4 __attribute__((ext_vector_type(4)));
typedef uint_t u32x4 __attribute__((ext_vector_type(4)));

// ---- bf16 helpers (manual, RNE) -------------------------------------------
__device__ __forceinline__ ushort_t f2bf(float f) {
    uint_t u = __float_as_uint(f);
    uint_t r = (u + 0x7fffu + ((u >> 16) & 1u)) >> 16;
    return (ushort_t)r;
}
__device__ __forceinline__ float bf2f(ushort_t v) {
    return __uint_as_float(((uint_t)v) << 16);
}

__device__ __forceinline__ float fast_rcp(float x) {
#if __has_builtin(__builtin_amdgcn_rcpf)
    return __builtin_amdgcn_rcpf(x);
#else
    return 1.f / x;
#endif
}
__device__ __forceinline__ float sigm(float x) {
    return fast_rcp(1.f + __expf(-x));
}
__device__ __forceinline__ float tanh_fast(float x) {
    return 1.f - 2.f * fast_rcp(1.f + __expf(2.f * x));
}

__device__ __forceinline__ fx4 mfma16(sh8 a, sh8 b, fx4 c) {
    return __builtin_amdgcn_mfma_f32_16x16x32_bf16(a, b, c, 0, 0, 0);
}

// split a fp32 pair into bf16 hi (truncated) + bf16 lo (residual, truncated).
// hi truncation is EXACTLY compensated by lo (a - bf2f(hi) is exact fp32,
// Sterbenz); total decomposition error <= 2^-16 relative. 8 cheap VALU ops,
// no rounding-mode dependence, no inline asm.
__device__ __forceinline__ void split2(float a, float b, uint_t& hi, uint_t& lo) {
    const uint_t ua = __float_as_uint(a), ub = __float_as_uint(b);
    hi = (ua >> 16) | (ub & 0xffff0000u);
    const float la = a - __uint_as_float(ua & 0xffff0000u);
    const float lb = b - __uint_as_float(ub & 0xffff0000u);
    const uint_t ula = __float_as_uint(la), ulb = __float_as_uint(lb);
    lo = (ula >> 16) | (ulb & 0xffff0000u);
}

// async global->LDS, 16B per lane (per-lane gptr; LDS dst = wave base + lane*16)
__device__ __forceinline__ void async_g2l(const ushort_t* g, ushort_t* l) {
#if __has_builtin(__builtin_amdgcn_global_load_lds)
    __builtin_amdgcn_global_load_lds(
        (const __attribute__((address_space(1))) unsigned int*)g,
        (__attribute__((address_space(3))) unsigned int*)l, 16, 0, 0);
#else
    *reinterpret_cast<uint4*>(l) = *reinterpret_cast<const uint4*>(g);
#endif
}

// raw barrier: drain LDS ops only; vmcnt waited explicitly where needed
#define BAR() asm volatile("s_waitcnt lgkmcnt(0)\n\ts_barrier" ::: "memory")

// ---------------------------------------------------------------------------
// Kernel 0: prepack weights.
//  y=0..2: recurrent Wh* fp32 [k][j] -> bf16 W^T  T[j*256+k]
//  y=3..5: input Wx* fp32 [k][j] -> split bf16 hi/lo W^T (for exact MFMA proj)
// ---------------------------------------------------------------------------
__global__ __launch_bounds__(256) void prepack_kernel(
    const float* __restrict__ Wz, const float* __restrict__ Wr,
    const float* __restrict__ Wh,
    const float* __restrict__ Xz, const float* __restrict__ Xr,
    const float* __restrict__ Xh,
    ushort_t* __restrict__ Tz, ushort_t* __restrict__ Tr,
    ushort_t* __restrict__ Th,
    ushort_t* __restrict__ Thi, ushort_t* __restrict__ Tlo)
{
    const int idx = blockIdx.x * 256 + threadIdx.x;  // 0..65535
    const int j = idx >> 8;
    const int k = idx & 255;
    const int y = blockIdx.y;
    if (y < 3) {
        const float* W = (y == 0) ? Wz : (y == 1) ? Wr : Wh;
        ushort_t* T = (y == 0) ? Tz : (y == 1) ? Tr : Th;
        T[idx] = f2bf(W[k * HD + j]);
    } else {
        const int g = y - 3;
        const float* W = (g == 0) ? Xz : (g == 1) ? Xr : Xh;
        const float wv = W[k * HD + j];
        const ushort_t hi = f2bf(wv);
        Thi[g * 65536 + idx] = hi;
        Tlo[g * 65536 + idx] = f2bf(wv - bf2f(hi));
    }
}

// ---------------------------------------------------------------------------
// Kernel 1: input projection as 3-term split-precision bf16 MFMA GEMM.
// C = (Xhi+Xlo)@(Whi+Wlo) ~= Xhi@Whi + Xlo@Whi + Xhi@Wlo  (lo*lo ~ 2^-18 dropped)
// Block: 256 thr (4 waves), M-tile 64 rows (one b, 64 t's), one gate (N=256).
// Wave w owns cols w*64..+63 (4 n-tiles) x 4 m-subtiles. A built on the fly
// from global fp32 X (split2); B sh8 frags straight from prepacked Thi/Tlo
// (L2-resident, 128KB/gate). Frag conventions identical to gru_recur
// (verified): A[m=l&15][k=(l>>4)*8+i], B[k][n=l&15], D[m=(l>>4)*4+r][n=l&15].
// ---------------------------------------------------------------------------
__global__ __launch_bounds__(256) void proj_mfma(
    const float* __restrict__ X,
    const ushort_t* __restrict__ Thi, const ushort_t* __restrict__ Tlo,
    const float* __restrict__ bz, const float* __restrict__ br,
    const float* __restrict__ bh,
    ushort_t* __restrict__ x5)
{
    __shared__ __align__(16) ushort_t ep[64 * 256];  // [row(64)][col(256)] 32KB

    const int tid  = threadIdx.x;
    const int lane = tid & 63;
    const int w    = tid >> 6;     // wave 0..3
    const int kq   = lane >> 4;
    const int ml   = lane & 15;
    const int m0   = blockIdx.x * 64;   // rows m0..m0+63 (b=m0>>10, t=m0&1023..)
    const int g    = blockIdx.y;        // gate

    const ushort_t* Bh = Thi + (size_t)g * 65536;
    const ushort_t* Bl = Tlo + (size_t)g * 65536;
    const float* bias = (g == 0) ? bz : (g == 1) ? br : bh;

    const fx4 zero4 = {0.f, 0.f, 0.f, 0.f};
    fx4 acc[4][4];  // [mt][nt]
#pragma unroll
    for (int mt = 0; mt < 4; ++mt)
#pragma unroll
        for (int nt = 0; nt < 4; ++nt) acc[mt][nt] = zero4;

    for (int kt = 0; kt < 8; ++kt) {
        const int koff = kq * 8 + kt * 32;
        sh8 bhi[4], blo[4];
#pragma unroll
        for (int nt = 0; nt < 4; ++nt) {
            const size_t rb = (size_t)(w * 64 + nt * 16 + ml) * 256 + koff;
            bhi[nt] = *reinterpret_cast<const sh8*>(Bh + rb);
            blo[nt] = *reinterpret_cast<const sh8*>(Bl + rb);
        }
#pragma unroll
        for (int mt = 0; mt < 4; ++mt) {
            const float* xp = X + (size_t)(m0 + mt * 16 + ml) * II + koff;
            const float4 f0 = *reinterpret_cast<const float4*>(xp);
            const float4 f1 = *reinterpret_cast<const float4*>(xp + 4);
            uint_t hv0, hv1, hv2, hv3, lv0, lv1, lv2, lv3;
            split2(f0.x, f0.y, hv0, lv0);
            split2(f0.z, f0.w, hv1, lv1);
            split2(f1.x, f1.y, hv2, lv2);
            split2(f1.z, f1.w, hv3, lv3);
            const u32x4 hq = {hv0, hv1, hv2, hv3};
            const u32x4 lq = {lv0, lv1, lv2, lv3};
            const sh8 ahi = __builtin_bit_cast(sh8, hq);
            const sh8 alo = __builtin_bit_cast(sh8, lq);
#pragma unroll
            for (int nt = 0; nt < 4; ++nt) {
                acc[mt][nt] = mfma16(ahi, bhi[nt], acc[mt][nt]);
                acc[mt][nt] = mfma16(alo, bhi[nt], acc[mt][nt]);
                acc[mt][nt] = mfma16(ahi, blo[nt], acc[mt][nt]);
            }
        }
    }

    // epilogue: bias + bf16, stage [64 rows][256 cols] in LDS
#pragma unroll
    for (int nt = 0; nt < 4; ++nt) {
        const int col = w * 64 + nt * 16 + ml;
        const float bv = bias[col];
#pragma unroll
        for (int mt = 0; mt < 4; ++mt)
#pragma unroll
            for (int r = 0; r < 4; ++r)
                ep[(mt * 16 + kq * 4 + r) * 256 + col] =
                    f2bf(acc[mt][nt][r] + bv);
    }
    __syncthreads();

    // store: row rr -> t = (m0&1023)+rr, b = m0>>10; 512B contiguous per row
    const int b   = m0 >> 10;
    const int t0m = m0 & 1023;
    const uint4* eps = reinterpret_cast<const uint4*>(ep);
#pragma unroll
    for (int it = 0; it < 8; ++it) {
        const int idx  = it * 256 + tid;  // 0..2047
        const int rr   = idx >> 5;
        const int part = idx & 31;
        uint4* dst = reinterpret_cast<uint4*>(
            x5 + ((size_t)(t0m + rr) * 64 + b) * 768 + g * 256) + part;
        *dst = eps[idx];
    }
}

// ---------------------------------------------------------------------------
// Kernel 2: recurrence, MFMA, 64 blocks x 1 batch. 512 threads (8 waves);
// wave owns 32 cols (2 tiles). 48 mfma/wave/step (M=1, rows 1-15 = dup).
// r4->r5 polish: shfl+x-reads hoisted above phase-1 MFMA (latency hidden
// under 32 MFMA issues); phase-2 split into 4 chains (8 chains/SIMD keeps
// the matrix pipe fed); launch_bounds(512,1) relaxes the register cap.
// ---------------------------------------------------------------------------
#define XB_U16 768  // 3*256 per (t,b)

__global__ __launch_bounds__(512, 1) void gru_recur(
    const ushort_t* __restrict__ x5,   // [t][b][g][j] bf16
    const ushort_t* __restrict__ Tz, const ushort_t* __restrict__ Tr,
    const ushort_t* __restrict__ Th,
    float* __restrict__ out)           // [B][T][256] then H_last [B][256]
{
    __shared__ __align__(16) ushort_t Hl[264];
    __shared__ __align__(16) ushort_t Rl[264];
    __shared__ __align__(16) ushort_t Xb[2][XB_U16];

    const int tid  = threadIdx.x;
    const int lane = tid & 63;
    const int w    = tid >> 6;      // wave 0..7
    const int kq   = lane >> 4;     // frag k-quadrant
    const int ml   = lane & 15;     // frag position
    const int cl   = lane & 31;     // epilogue column within wave
    const int gate = lane >> 5;     // 0: z-duty, 1: r-duty
    const int sel  = (lane >> 4) & 1;  // which tile's acc reg
    const int j    = w * 32 + cl;   // hidden column this lane handles
    const int b    = blockIdx.x;    // batch 0..63

    // ---- all three W^T in regs (VGPR/AGPR): 3 x 2 x 8 x 4 = 192 ----
    sh8 wz[2][8], wr[2][8], wh[2][8];
#pragma unroll
    for (int cc = 0; cc < 2; ++cc) {
        const int jw = w * 32 + cc * 16 + ml;
        const size_t rb = (size_t)jw * 256 + kq * 8;
#pragma unroll
        for (int kt = 0; kt < 8; ++kt) {
            wz[cc][kt] = *reinterpret_cast<const sh8*>(Tz + rb + kt * 32);
            wr[cc][kt] = *reinterpret_cast<const sh8*>(Tr + rb + kt * 32);
            wh[cc][kt] = *reinterpret_cast<const sh8*>(Th + rb + kt * 32);
        }
    }

    // zero H/R rows (264 u16 = 132 u32 each)
    if (tid < 132) { ((uint_t*)Hl)[tid] = 0u; ((uint_t*)Rl)[tid] = 0u; }

    float hk = 0.f;  // lanes 0-31: H[b][j]; lanes 32-63 unused

    // stage x[0]: 768 u16 = 1536B = 96 lanes x 16B
    if (tid < 96) async_g2l(x5 + (size_t)b * XB_U16 + tid * 8, &Xb[0][tid * 8]);
    asm volatile("s_waitcnt vmcnt(0)" ::: "memory");
    __syncthreads();

    const ushort_t* harow = Hl + kq * 8;
    const ushort_t* rarow = Rl + kq * 8;
    float* ob = out + (size_t)b * TT * HD;

    const fx4 zero4 = {0.f, 0.f, 0.f, 0.f};
    int cur = 0;
    for (int t = 0; t < TT; ++t) {
        // issue async staging of x[t+1] into the other buffer
        {
            const int tn = (t < TT - 1) ? t + 1 : t;
            if (tid < 96)
                async_g2l(x5 + ((size_t)tn * 64 + b) * XB_U16 + tid * 8,
                          &Xb[cur ^ 1][tid * 8]);
        }
        const ushort_t* xc = Xb[cur];

        // hoisted: h[j] into r-lanes + x reads; all hidden under phase-1 MFMAs
        const float hsh  = __shfl(hk, cl);
        const float xg   = bf2f(xc[gate * 256 + j]);
        const float xh_r = bf2f(xc[512 + j]);

        // ---- phase 1: Z, R = sigmoid(x + H @ W) ----
        fx4 az0 = zero4, az1 = zero4, ar0 = zero4, ar1 = zero4;
#pragma unroll
        for (int kt = 0; kt < 8; ++kt) {
            const sh8 a = *reinterpret_cast<const sh8*>(harow + kt * 32);
            az0 = mfma16(a, wz[0][kt], az0);
            az1 = mfma16(a, wz[1][kt], az1);
            ar0 = mfma16(a, wr[0][kt], ar0);
            ar1 = mfma16(a, wr[1][kt], ar1);
        }
        // every lane's reg[0] = D[0][lane&15] (A rows duplicated) -> no shfl
        const float v0 = gate ? ar0[0] : az0[0];
        const float v1 = gate ? ar1[0] : az1[0];
        const float v  = sel ? v1 : v0;
        const float s  = sigm(xg + v);
        const float zreg = s;  // meaningful in lanes 0-31
        if (gate) Rl[j] = f2bf(s * hsh);
        BAR();  // R*H visible to all waves

        // ---- phase 2: H~ = tanh(xh + (R*H) @ Whh); blend ----
        // 4 chains (vs 2) -> 8 chains/SIMD, keeps matrix pipe fed
        fx4 ah0a = zero4, ah0b = zero4, ah1a = zero4, ah1b = zero4;
#pragma unroll
        for (int kt = 0; kt < 8; kt += 2) {
            const sh8 a0 = *reinterpret_cast<const sh8*>(rarow + kt * 32);
            const sh8 a1 = *reinterpret_cast<const sh8*>(rarow + (kt + 1) * 32);
            ah0a = mfma16(a0, wh[0][kt], ah0a);
            ah1a = mfma16(a0, wh[1][kt], ah1a);
            ah0b = mfma16(a1, wh[0][kt + 1], ah0b);
            ah1b = mfma16(a1, wh[1][kt + 1], ah1b);
        }
        float hn = hk;
        if (!gate) {  // lanes 0-31 finish their column
            const float va = sel ? (ah1a[0] + ah1b[0]) : (ah0a[0] + ah0b[0]);
            const float th = tanh_fast(xh_r + va);
            hn = zreg * hk + (1.f - zreg) * th;
            hk = hn;
            Hl[j] = f2bf(hn);
        }
        asm volatile("s_waitcnt vmcnt(0)" ::: "memory");  // x[t+1] staged
        BAR();  // H + x-buffer safe for next step

        // out store after the barrier (fire-and-forget; drained by the NEXT
        // iteration's vmcnt(0), a full step later)
        if (!gate) ob[(size_t)t * HD + j] = hn;
        cur ^= 1;
    }

    // H_last
    if (!gate) out[(size_t)BB * TT * HD + (size_t)b * HD + j] = hk;
}

// ---------------------------------------------------------------------------
extern "C" void kernel_launch(void* const* d_in, const int* in_sizes, int n_in,
                              void* d_out, int out_size, void* d_ws, size_t ws_size,
                              hipStream_t stream) {
    const float* X   = (const float*)d_in[0];
    const float* Wxz = (const float*)d_in[1];
    const float* Whz = (const float*)d_in[2];
    const float* bz  = (const float*)d_in[3];
    const float* Wxr = (const float*)d_in[4];
    const float* Whr = (const float*)d_in[5];
    const float* br  = (const float*)d_in[6];
    const float* Wxh = (const float*)d_in[7];
    const float* Whh = (const float*)d_in[8];
    const float* bh  = (const float*)d_in[9];
    float* out = (float*)d_out;

    // ws layout: [0, 96 MiB) x5 bf16 [t][b][g][j]; then 3x128KiB recurrent W^T;
    // then 3x128KiB input-W^T hi; then 3x128KiB input-W^T lo  (~97.2 MiB)
    const size_t X5_BYTES = (size_t)TT * BB * 3 * 256 * 2;
    ushort_t* x5  = (ushort_t*)d_ws;
    ushort_t* Tz  = (ushort_t*)((char*)d_ws + X5_BYTES);
    ushort_t* Tr  = Tz + HD * HD;
    ushort_t* Th  = Tr + HD * HD;
    ushort_t* Thi = Th + HD * HD;            // 3 * 65536
    ushort_t* Tlo = Thi + 3 * HD * HD;       // 3 * 65536

    prepack_kernel<<<dim3(256, 6), 256, 0, stream>>>(
        Whz, Whr, Whh, Wxz, Wxr, Wxh, Tz, Tr, Th, Thi, Tlo);
    proj_mfma<<<dim3(1024, 3), 256, 0, stream>>>(
        X, Thi, Tlo, bz, br, bh, x5);
    gru_recur<<<dim3(64), 512, 0, stream>>>(x5, Tz, Tr, Th, out);
}